// Round 1
// baseline (19.066 us; speedup 1.0000x reference)
//
#include <hip/hip_runtime.h>

// HWnet: per-sample nearest-entry lookup in a sorted 1024-entry grid,
// then a 17-wide sharpened softmax over the neighboring window,
// then a weighted sum of vector_table (V=1).
//
// N=262144, T=1024, E=8, V=1. Memory footprint ~2MB -> launch-overhead bound.

constexpr int T_SIZE = 1024;
constexpr int E_SIZE = 8;
constexpr int WIN    = 2 * E_SIZE + 1;   // 17
constexpr int BLOCK  = 256;

__global__ __launch_bounds__(BLOCK) void hwnet_kernel(
    const float* __restrict__ inputs,
    const float* __restrict__ eval_t,
    const float* __restrict__ take_t,
    const float* __restrict__ vec_t,
    float* __restrict__ out,
    int n)
{
    __shared__ float s_eval[T_SIZE];
    __shared__ float s_take[T_SIZE];
    __shared__ float s_vec[T_SIZE];

    // Cooperative stage of the three tables (12 KB total) into LDS.
    #pragma unroll
    for (int i = threadIdx.x; i < T_SIZE; i += BLOCK) {
        s_eval[i] = eval_t[i];
        s_take[i] = take_t[i];
        s_vec[i]  = vec_t[i];
    }
    __syncthreads();

    const int gid = blockIdx.x * BLOCK + threadIdx.x;
    if (gid >= n) return;

    const float x = inputs[gid];

    // lower_bound: first index i with s_eval[i] >= x   (table is sorted).
    int lo = 0, hi = T_SIZE;
    #pragma unroll
    for (int it = 0; it < 10; ++it) {          // 2^10 = 1024
        const int mid = (lo + hi) >> 1;
        if (s_eval[mid] < x) lo = mid + 1; else hi = mid;
    }

    // Nearest entry, replicating jnp.argmin((x - e)^2) semantics:
    // squares computed in f32, ties -> FIRST (lowest) index.
    int idx;
    if (lo == 0) {
        idx = 0;
    } else if (lo == T_SIZE) {
        idx = T_SIZE - 1;
    } else {
        const float d0 = x - s_eval[lo - 1];
        const float d1 = x - s_eval[lo];
        idx = (d0 * d0 <= d1 * d1) ? (lo - 1) : lo;
    }
    // Walk down through rounded-square ties / duplicate table values so we
    // land on the FIRST index attaining the minimal squared distance.
    while (idx > 0) {
        const float dp = x - s_eval[idx - 1];
        const float dc = x - s_eval[idx];
        if (dp * dp <= dc * dc) --idx; else break;
    }

    const float take = s_take[idx];

    // Window base: clip(idx, E, T-1-E) - E
    int c = idx;
    if (c < E_SIZE) c = E_SIZE;
    if (c > T_SIZE - 1 - E_SIZE) c = T_SIZE - 1 - E_SIZE;
    const int base = c - E_SIZE;

    // Sharpened softmax over the 17-entry window (max-subtracted).
    float sc[WIN];
    float m = -INFINITY;
    #pragma unroll
    for (int k = 0; k < WIN; ++k) {
        const float d = x - s_eval[base + k];
        const float s = -(d * d) * take;
        sc[k] = s;
        m = fmaxf(m, s);
    }
    float sum = 0.0f, acc = 0.0f;
    #pragma unroll
    for (int k = 0; k < WIN; ++k) {
        const float e = __expf(sc[k] - m);
        sum += e;
        acc += e * s_vec[base + k];
    }
    out[gid] = acc / sum;
}

extern "C" void kernel_launch(void* const* d_in, const int* in_sizes, int n_in,
                              void* d_out, int out_size, void* d_ws, size_t ws_size,
                              hipStream_t stream) {
    const float* inputs = (const float*)d_in[0];
    const float* eval_t = (const float*)d_in[1];
    const float* take_t = (const float*)d_in[2];
    const float* vec_t  = (const float*)d_in[3];
    float* out = (float*)d_out;

    const int n = in_sizes[0];                  // N (inputs is (N,1))
    const int grid = (n + BLOCK - 1) / BLOCK;   // 1024 blocks
    hwnet_kernel<<<grid, BLOCK, 0, stream>>>(inputs, eval_t, take_t, vec_t, out, n);
}

// Round 2
// 11.074 us; speedup vs baseline: 1.7216x; 1.7216x over previous
//
#include <hip/hip_runtime.h>

// HWnet: per-sample nearest-entry lookup in a sorted 1024-entry grid,
// then a 17-wide sharpened softmax over the neighboring window,
// then a weighted sum of vector_table (V=1).
//
// N=262144, T=1024, E=8, V=1. ~2MB real traffic -> latency/launch bound.
//
// Round-2 changes vs round 1:
//  - padded LDS copy of eval for the binary search: tree-level probe
//    addresses 2^k*odd are all congruent mod 32 -> same-bank 4..32-way
//    conflicts; pad i -> i + (i>>5) spreads them across banks.
//  - 2 samples/thread (float2): two independent interleaved binary
//    searches per thread double MLP; 512 blocks = exactly 2/CU.
//  - softmax scores are always <= 0 -> exp can't overflow -> drop the
//    max-subtraction pass; single fused loop.
//  - (eval, vec) interleaved as float2 in LDS: 17x ds_read_b64 instead
//    of 34x ds_read_b32 in the window loop.

constexpr int T_SIZE = 1024;
constexpr int E_SIZE = 8;
constexpr int WIN    = 2 * E_SIZE + 1;   // 17
constexpr int BLOCK  = 256;
constexpr int T_PAD  = T_SIZE + (T_SIZE >> 5);  // 1056

__device__ __forceinline__ float hwnet_finish(
    float x, int lo,
    const float2* __restrict__ s_ev,
    const float* __restrict__ s_take)
{
    // Nearest entry, replicating jnp.argmin((x-e)^2) semantics:
    // squares in f32, ties -> FIRST (lowest) index.
    int idx;
    if (lo == 0) {
        idx = 0;
    } else if (lo == T_SIZE) {
        idx = T_SIZE - 1;
    } else {
        const float d0 = x - s_ev[lo - 1].x;
        const float d1 = x - s_ev[lo].x;
        idx = (d0 * d0 <= d1 * d1) ? (lo - 1) : lo;
    }
    // Walk down through rounded-square ties / duplicates -> first minimum.
    while (idx > 0) {
        const float dp = x - s_ev[idx - 1].x;
        const float dc = x - s_ev[idx].x;
        if (dp * dp <= dc * dc) --idx; else break;
    }

    const float take = s_take[idx];

    int c = idx;
    if (c < E_SIZE) c = E_SIZE;
    if (c > T_SIZE - 1 - E_SIZE) c = T_SIZE - 1 - E_SIZE;
    const int base = c - E_SIZE;

    // Scores -(d^2)*take <= 0 -> exp in (0,1]; no max-subtraction needed.
    float sum = 0.0f, acc = 0.0f;
    #pragma unroll
    for (int k = 0; k < WIN; ++k) {
        const float2 ev = s_ev[base + k];
        const float d = x - ev.x;
        const float e = __expf(-(d * d) * take);
        sum += e;
        acc += e * ev.y;
    }
    return acc / sum;
}

__global__ __launch_bounds__(BLOCK) void hwnet_kernel(
    const float* __restrict__ inputs,
    const float* __restrict__ eval_t,
    const float* __restrict__ take_t,
    const float* __restrict__ vec_t,
    float* __restrict__ out,
    int n)
{
    __shared__ float  s_evs[T_PAD];    // padded eval copy (binary search)
    __shared__ float2 s_ev[T_SIZE];    // interleaved (eval, vec) (window)
    __shared__ float  s_take[T_SIZE];

    // Vectorized stage: 256 threads x 4 entries = 1024.
    {
        const int i4 = threadIdx.x * 4;
        const float4 e4 = *reinterpret_cast<const float4*>(eval_t + i4);
        const float4 t4 = *reinterpret_cast<const float4*>(take_t + i4);
        const float4 v4 = *reinterpret_cast<const float4*>(vec_t + i4);
        const float ee[4] = {e4.x, e4.y, e4.z, e4.w};
        const float tt[4] = {t4.x, t4.y, t4.z, t4.w};
        const float vv[4] = {v4.x, v4.y, v4.z, v4.w};
        #pragma unroll
        for (int k = 0; k < 4; ++k) {
            const int i = i4 + k;
            s_evs[i + (i >> 5)] = ee[k];
            s_ev[i] = make_float2(ee[k], vv[k]);
            s_take[i] = tt[k];
        }
    }
    __syncthreads();

    const int gid2 = blockIdx.x * BLOCK + threadIdx.x;
    const int n2 = n >> 1;
    if (gid2 < n2) {
        const float2 x2 = reinterpret_cast<const float2*>(inputs)[gid2];

        // Two independent interleaved binary searches (lower_bound).
        int lo0 = 0, hi0 = T_SIZE, lo1 = 0, hi1 = T_SIZE;
        #pragma unroll
        for (int it = 0; it < 10; ++it) {      // 2^10 = 1024
            const int m0 = (lo0 + hi0) >> 1;
            const int m1 = (lo1 + hi1) >> 1;
            const float e0 = s_evs[m0 + (m0 >> 5)];
            const float e1 = s_evs[m1 + (m1 >> 5)];
            if (e0 < x2.x) lo0 = m0 + 1; else hi0 = m0;
            if (e1 < x2.y) lo1 = m1 + 1; else hi1 = m1;
        }

        const float r0 = hwnet_finish(x2.x, lo0, s_ev, s_take);
        const float r1 = hwnet_finish(x2.y, lo1, s_ev, s_take);
        reinterpret_cast<float2*>(out)[gid2] = make_float2(r0, r1);
    }

    // Odd-n tail (dead for N=262144, kept for safety).
    if ((n & 1) && gid2 == 0) {
        const float x = inputs[n - 1];
        int lo = 0, hi = T_SIZE;
        for (int it = 0; it < 10; ++it) {
            const int mid = (lo + hi) >> 1;
            if (s_evs[mid + (mid >> 5)] < x) lo = mid + 1; else hi = mid;
        }
        out[n - 1] = hwnet_finish(x, lo, s_ev, s_take);
    }
}

extern "C" void kernel_launch(void* const* d_in, const int* in_sizes, int n_in,
                              void* d_out, int out_size, void* d_ws, size_t ws_size,
                              hipStream_t stream) {
    const float* inputs = (const float*)d_in[0];
    const float* eval_t = (const float*)d_in[1];
    const float* take_t = (const float*)d_in[2];
    const float* vec_t  = (const float*)d_in[3];
    float* out = (float*)d_out;

    const int n = in_sizes[0];                       // N
    const int n2 = n >> 1;
    const int grid = (n2 + BLOCK - 1) / BLOCK;       // 512 blocks
    hwnet_kernel<<<grid, BLOCK, 0, stream>>>(inputs, eval_t, take_t, vec_t, out, n);
}